// Round 1
// baseline (1152.148 us; speedup 1.0000x reference)
//
#include <hip/hip_runtime.h>
#include <hip/hip_bf16.h>

typedef __bf16 bf16_t;
typedef __bf16 bf16x8 __attribute__((ext_vector_type(8)));
typedef __bf16 bf16x4 __attribute__((ext_vector_type(4)));
typedef float f32x4 __attribute__((ext_vector_type(4)));

#define DI __device__ __forceinline__

DI f32x4 mfma16(bf16x8 a, bf16x8 b, f32x4 c) {
  return __builtin_amdgcn_mfma_f32_16x16x32_bf16(a, b, c, 0, 0, 0);
}

__constant__ int GEO_c[15] = {1,2,3,4,5,6,8,10,22,23,29,31,32,33,43};
__constant__ int POS_c[11] = {9,16,17,20,27,30,36,42,48,49,50};
__constant__ int SEM_c[24] = {7,11,12,13,14,15,18,19,21,24,25,26,28,34,35,37,38,39,40,41,44,45,46,47};

// ---------- prep: transpose f32 [K][N] -> bf16 [N][K] ----------
__global__ void k_transpose(const float* __restrict__ src, bf16_t* __restrict__ dst,
                            int K, int N) {
  __shared__ float s[64][65];
  int n0 = blockIdx.x * 64, k0 = blockIdx.y * 64;
  int t = threadIdx.x;
#pragma unroll
  for (int i = 0; i < 4; ++i) {
    int idx = t + i * 256; int kr = idx >> 4, seg = idx & 15;
    float4 v = *(const float4*)(src + (size_t)(k0 + kr) * N + n0 + seg * 4);
    s[kr][seg * 4 + 0] = v.x; s[kr][seg * 4 + 1] = v.y;
    s[kr][seg * 4 + 2] = v.z; s[kr][seg * 4 + 3] = v.w;
  }
  __syncthreads();
#pragma unroll
  for (int i = 0; i < 4; ++i) {
    int idx = t + i * 256; int nr = idx >> 4, seg = idx & 15;
    bf16x4 h;
    h[0] = (bf16_t)s[seg * 4 + 0][nr]; h[1] = (bf16_t)s[seg * 4 + 1][nr];
    h[2] = (bf16_t)s[seg * 4 + 2][nr]; h[3] = (bf16_t)s[seg * 4 + 3][nr];
    *(bf16x4*)(dst + (size_t)(n0 + nr) * K + k0 + seg * 4) = h;
  }
}

// ---------- prep: pack Wc*/Wv* into [64][4096] bf16 (cols 54..63 zero), bcv ----------
DI void cat_map(int j, int& which, int& sub, int& nc) {
  if (j < 15)      { which = 0; sub = j;      nc = 15; }
  else if (j < 26) { which = 1; sub = j - 15; nc = 11; }
  else if (j < 50) { which = 2; sub = j - 26; nc = 24; }
  else if (j < 54) { which = 3; sub = j - 50; nc = 4;  }
  else             { which = 4; sub = 0;      nc = 1;  }
}

__global__ void k_pack_cat(const float* __restrict__ Wc1, const float* __restrict__ Wc2,
                           const float* __restrict__ Wc3, const float* __restrict__ Wcs,
                           const float* __restrict__ Wv1, const float* __restrict__ Wv2,
                           const float* __restrict__ Wv3, const float* __restrict__ Wvs,
                           const float* __restrict__ bc1, const float* __restrict__ bc2,
                           const float* __restrict__ bc3, const float* __restrict__ bcs,
                           const float* __restrict__ bv1, const float* __restrict__ bv2,
                           const float* __restrict__ bv3, const float* __restrict__ bvs,
                           bf16_t* __restrict__ WcatT, bf16_t* __restrict__ WvcatT,
                           float* __restrict__ bcv) {
  int j = blockIdx.x, t = threadIdx.x;
  int which, sub, nc; cat_map(j, which, sub, nc);
  const float* Wc = which == 0 ? Wc1 : which == 1 ? Wc2 : which == 2 ? Wc3 : Wcs;
  const float* Wv = which == 0 ? Wv1 : which == 1 ? Wv2 : which == 2 ? Wv3 : Wvs;
  for (int i = 0; i < 16; ++i) {
    int k = t + i * 256;
    float vc = 0.f, vv = 0.f;
    if (which < 4) { vc = Wc[(size_t)k * nc + sub]; vv = Wv[(size_t)k * nc + sub]; }
    WcatT[(size_t)j * 4096 + k] = (bf16_t)vc;
    WvcatT[(size_t)j * 4096 + k] = (bf16_t)vv;
  }
  if (t == 0) {
    float b = 0.f;
    if (which < 4) {
      const float* bc = which == 0 ? bc1 : which == 1 ? bc2 : which == 2 ? bc3 : bcs;
      const float* bv = which == 0 ? bv1 : which == 1 ? bv2 : which == 2 ? bv3 : bvs;
      b = bc[sub] + bv[sub];
    }
    bcv[j] = b;
  }
}

// ---------- er = edge_ctx @ W_post_emb + b  -> bf16 [8192][1024] ----------
__global__ __launch_bounds__(256) void k_er(const float* __restrict__ ec,
                                            const bf16_t* __restrict__ WpeT,
                                            const float* __restrict__ bpe,
                                            bf16_t* __restrict__ er) {
  __shared__ bf16_t sA[128 * 64];
  __shared__ bf16_t sB[128 * 64];
  const int m0 = blockIdx.y * 128, n0 = blockIdx.x * 128;
  const int t = threadIdx.x, w = t >> 6, l = t & 63;
  const int lrow = l & 15, lkB = (l >> 4) << 4;

  f32x4 acc[2][8];
#pragma unroll
  for (int rf = 0; rf < 2; ++rf)
#pragma unroll
    for (int cf = 0; cf < 8; ++cf) { f32x4 z = {0.f, 0.f, 0.f, 0.f}; acc[rf][cf] = z; }

  for (int kk = 0; kk < 512; kk += 64) {
    __syncthreads();
#pragma unroll
    for (int i = 0; i < 8; ++i) {
      int idx = t + i * 256; int row = idx >> 4, seg = idx & 15;
      float4 v = *(const float4*)(ec + (size_t)(m0 + row) * 512 + kk + seg * 4);
      bf16x4 h; h[0] = (bf16_t)v.x; h[1] = (bf16_t)v.y; h[2] = (bf16_t)v.z; h[3] = (bf16_t)v.w;
      *(bf16x4*)((char*)sA + (row << 7) + ((seg << 3) ^ ((row & 7) << 4))) = h;
    }
#pragma unroll
    for (int i = 0; i < 4; ++i) {
      int idx = t + i * 256; int col = idx >> 3, seg = idx & 7;
      bf16x8 v = *(const bf16x8*)(WpeT + (size_t)(n0 + col) * 512 + kk + seg * 8);
      *(bf16x8*)((char*)sB + (col << 7) + ((seg << 4) ^ ((col & 7) << 4))) = v;
    }
    __syncthreads();
#pragma unroll
    for (int ks = 0; ks < 2; ++ks) {
      bf16x8 af[2], bfr[8];
#pragma unroll
      for (int rf = 0; rf < 2; ++rf) {
        int row = w * 32 + rf * 16 + lrow;
        af[rf] = *(const bf16x8*)((const char*)sA + (row << 7) + (((ks << 6) | lkB) ^ ((row & 7) << 4)));
      }
#pragma unroll
      for (int cf = 0; cf < 8; ++cf) {
        int col = cf * 16 + lrow;
        bfr[cf] = *(const bf16x8*)((const char*)sB + (col << 7) + (((ks << 6) | lkB) ^ ((col & 7) << 4)));
      }
#pragma unroll
      for (int rf = 0; rf < 2; ++rf)
#pragma unroll
        for (int cf = 0; cf < 8; ++cf)
          acc[rf][cf] = mfma16(af[rf], bfr[cf], acc[rf][cf]);
    }
  }
#pragma unroll
  for (int cf = 0; cf < 8; ++cf) {
    float bias = bpe[n0 + cf * 16 + lrow];
#pragma unroll
    for (int rf = 0; rf < 2; ++rf)
#pragma unroll
      for (int r = 0; r < 4; ++r) {
        int row = m0 + w * 32 + rf * 16 + ((l >> 4) << 2) + r;
        er[(size_t)row * 1024 + n0 + cf * 16 + lrow] = (bf16_t)(acc[rf][cf][r] + bias);
      }
  }
}

// ---------- main fused kernel ----------
DI void gemm2(const bf16_t* sP, const bf16_t* sWl, f32x4 (&acc)[2][4],
              int w, int lrow, int lkB) {
#pragma unroll
  for (int ks = 0; ks < 4; ++ks) {
    bf16x8 af[2], bfr[4];
#pragma unroll
    for (int rf = 0; rf < 2; ++rf) {
      int row = w * 32 + rf * 16 + lrow;
      af[rf] = *(const bf16x8*)((const char*)sP + (row << 8) + (((ks << 6) | lkB) ^ ((row & 7) << 4)));
    }
#pragma unroll
    for (int cf = 0; cf < 4; ++cf) {
      int col = cf * 16 + lrow;
      bfr[cf] = *(const bf16x8*)((const char*)sWl + (col << 8) + (((ks << 6) | lkB) ^ ((col & 7) << 4)));
    }
#pragma unroll
    for (int rf = 0; rf < 2; ++rf)
#pragma unroll
      for (int cf = 0; cf < 4; ++cf)
        acc[rf][cf] = mfma16(af[rf], bfr[cf], acc[rf][cf]);
  }
}

__global__ __launch_bounds__(256, 2) void k_main(
    const bf16_t* __restrict__ er, const bf16_t* __restrict__ WpcT,
    const float* __restrict__ bpc,
    const bf16_t* __restrict__ WcatT, const bf16_t* __restrict__ WvcatT,
    const float* __restrict__ bcv,
    const int* __restrict__ pair_idx, const int* __restrict__ pair_pred,
    const float* __restrict__ vis, const float* __restrict__ freq,
    float* __restrict__ out) {
  __shared__ bf16_t sA[128 * 64];     // ctx tile [row][64k], swizzled
  __shared__ bf16_t sB[128 * 64];     // Wpc tile [col][64k], swizzled
  __shared__ bf16_t sPV[128 * 128];   // P or Vis tile [row][128k], swizzled
  __shared__ bf16_t sW[64 * 128];     // Wcat/Wvcat tile [col][128k], swizzled

  const int t = threadIdx.x;
  const int w = t >> 6, l = t & 63;
  const int lrow = l & 15;
  const int lkB = (l >> 4) << 4;
  const int p0 = blockIdx.x * 128;

  int r0[4], r1[4];
#pragma unroll
  for (int i = 0; i < 4; ++i) {
    int prow = p0 + (t >> 3) + (i << 5);
    r0[i] = pair_idx[prow * 2];
    r1[i] = pair_idx[prow * 2 + 1];
  }

  f32x4 acc[2][4];
#pragma unroll
  for (int rf = 0; rf < 2; ++rf)
#pragma unroll
    for (int cf = 0; cf < 4; ++cf) { f32x4 z = {0.f, 0.f, 0.f, 0.f}; acc[rf][cf] = z; }

#pragma unroll 1
  for (int nc = 0; nc < 32; ++nc) {
    const size_t nbase = (size_t)nc * 128;
    f32x4 pacc[2][8];
#pragma unroll
    for (int rf = 0; rf < 2; ++rf)
#pragma unroll
      for (int cf = 0; cf < 8; ++cf) { f32x4 z = {0.f, 0.f, 0.f, 0.f}; pacc[rf][cf] = z; }

#pragma unroll 1
    for (int kk = 0; kk < 1024; kk += 64) {
      __syncthreads();
      const int aSeg = t & 7;
#pragma unroll
      for (int i = 0; i < 4; ++i) {
        int row = (t >> 3) + (i << 5);
        int sr = (kk < 512) ? r0[i] : r1[i];
        bf16x8 v = *(const bf16x8*)(er + (size_t)sr * 1024 + kk + aSeg * 8);
        *(bf16x8*)((char*)sA + (row << 7) + ((aSeg << 4) ^ ((row & 7) << 4))) = v;
      }
#pragma unroll
      for (int i = 0; i < 4; ++i) {
        int col = (t >> 3) + (i << 5);
        bf16x8 v = *(const bf16x8*)(WpcT + (nbase + col) * 1024 + kk + aSeg * 8);
        *(bf16x8*)((char*)sB + (col << 7) + ((aSeg << 4) ^ ((col & 7) << 4))) = v;
      }
      __syncthreads();
#pragma unroll
      for (int ks = 0; ks < 2; ++ks) {
        bf16x8 af[2], bfr[8];
#pragma unroll
        for (int rf = 0; rf < 2; ++rf) {
          int row = w * 32 + rf * 16 + lrow;
          af[rf] = *(const bf16x8*)((const char*)sA + (row << 7) + (((ks << 6) | lkB) ^ ((row & 7) << 4)));
        }
#pragma unroll
        for (int cf = 0; cf < 8; ++cf) {
          int col = cf * 16 + lrow;
          bfr[cf] = *(const bf16x8*)((const char*)sB + (col << 7) + (((ks << 6) | lkB) ^ ((col & 7) << 4)));
        }
#pragma unroll
        for (int rf = 0; rf < 2; ++rf)
#pragma unroll
          for (int cf = 0; cf < 8; ++cf)
            pacc[rf][cf] = mfma16(af[rf], bfr[cf], pacc[rf][cf]);
      }
    }

    // P = relu(pacc + b_post_cat) -> sPV (bf16, swizzled); wave-local rows only
#pragma unroll
    for (int cf = 0; cf < 8; ++cf) {
      float bias = bpc[nbase + cf * 16 + lrow];
#pragma unroll
      for (int rf = 0; rf < 2; ++rf)
#pragma unroll
        for (int r = 0; r < 4; ++r) {
          int row = w * 32 + rf * 16 + ((l >> 4) << 2) + r;
          float x = fmaxf(pacc[rf][cf][r] + bias, 0.f);
          *(bf16_t*)((char*)sPV + (row << 8) + (((cf * 16 + lrow) << 1) ^ ((row & 7) << 4))) = (bf16_t)x;
        }
    }
    // stage Wcat chunk
#pragma unroll
    for (int i = 0; i < 4; ++i) {
      int j = (t >> 4) + (i << 4), seg = t & 15;
      bf16x8 v = *(const bf16x8*)(WcatT + (size_t)j * 4096 + nbase + seg * 8);
      *(bf16x8*)((char*)sW + (j << 8) + ((seg << 4) ^ ((j & 7) << 4))) = v;
    }
    __syncthreads();
    gemm2(sPV, sW, acc, w, lrow, lkB);     // acc += P @ Wcat
    __syncthreads();
    // stage vis chunk (f32 -> bf16) and Wvcat chunk
#pragma unroll
    for (int i = 0; i < 16; ++i) {
      int row = (t >> 5) + (i << 3), seg = t & 31;
      float4 v = *(const float4*)(vis + (size_t)(p0 + row) * 4096 + nbase + seg * 4);
      bf16x4 h; h[0] = (bf16_t)v.x; h[1] = (bf16_t)v.y; h[2] = (bf16_t)v.z; h[3] = (bf16_t)v.w;
      *(bf16x4*)((char*)sPV + (row << 8) + ((seg << 3) ^ ((row & 7) << 4))) = h;
    }
#pragma unroll
    for (int i = 0; i < 4; ++i) {
      int j = (t >> 4) + (i << 4), seg = t & 15;
      bf16x8 v = *(const bf16x8*)(WvcatT + (size_t)j * 4096 + nbase + seg * 8);
      *(bf16x8*)((char*)sW + (j << 8) + ((seg << 4) ^ ((j & 7) << 4))) = v;
    }
    __syncthreads();
    gemm2(sPV, sW, acc, w, lrow, lkB);     // acc += Vis @ Wvcat
  }

  // epilogue: acc -> LDS f32, then per-pair bias gather + logsumexp + writes
  __syncthreads();
  float* sF = (float*)sPV;
#pragma unroll
  for (int cf = 0; cf < 4; ++cf) {
    float bb = bcv[cf * 16 + lrow];
#pragma unroll
    for (int rf = 0; rf < 2; ++rf)
#pragma unroll
      for (int r = 0; r < 4; ++r) {
        int row = w * 32 + rf * 16 + ((l >> 4) << 2) + r;
        sF[row * 64 + cf * 16 + lrow] = acc[rf][cf][r] + bb;
      }
  }
  __syncthreads();
  if (t < 128) {
    int p = p0 + t;
    const float* f = freq + ((size_t)pair_pred[p * 2] * 151 + pair_pred[p * 2 + 1]) * 51;
    const float* rowv = sF + t * 64;
    float e1 = 0.f, e2 = 0.f, e3 = 0.f;
#pragma unroll
    for (int c = 0; c < 15; ++c) {
      float fb = f[GEO_c[c]]; e1 += expf(fb);
      out[(size_t)p * 15 + c] = rowv[c] + fb;
    }
#pragma unroll
    for (int c = 0; c < 11; ++c) {
      float fb = f[POS_c[c]]; e2 += expf(fb);
      out[491520 + (size_t)p * 11 + c] = rowv[15 + c] + fb;
    }
#pragma unroll
    for (int c = 0; c < 24; ++c) {
      float fb = f[SEM_c[c]]; e3 += expf(fb);
      out[851968 + (size_t)p * 24 + c] = rowv[26 + c] + fb;
    }
    out[1638400 + (size_t)p * 4 + 0] = rowv[50] + f[0];
    out[1638400 + (size_t)p * 4 + 1] = rowv[51] + logf(e1);
    out[1638400 + (size_t)p * 4 + 2] = rowv[52] + logf(e2);
    out[1638400 + (size_t)p * 4 + 3] = rowv[53] + logf(e3);
  }
}

extern "C" void kernel_launch(void* const* d_in, const int* in_sizes, int n_in,
                              void* d_out, int out_size, void* d_ws, size_t ws_size,
                              hipStream_t stream) {
  const float* edge_ctx  = (const float*)d_in[0];
  const int*   pair_idx  = (const int*)d_in[1];
  const float* vis_rep   = (const float*)d_in[2];
  const int*   pair_pred = (const int*)d_in[3];
  const float* Wpe = (const float*)d_in[4];
  const float* bpe = (const float*)d_in[5];
  const float* Wpc = (const float*)d_in[6];
  const float* bpc = (const float*)d_in[7];
  const float* Wc1 = (const float*)d_in[8];  const float* bc1 = (const float*)d_in[9];
  const float* Wc2 = (const float*)d_in[10]; const float* bc2 = (const float*)d_in[11];
  const float* Wc3 = (const float*)d_in[12]; const float* bc3 = (const float*)d_in[13];
  const float* Wcs = (const float*)d_in[14]; const float* bcs = (const float*)d_in[15];
  const float* Wv1 = (const float*)d_in[16]; const float* bv1 = (const float*)d_in[17];
  const float* Wv2 = (const float*)d_in[18]; const float* bv2 = (const float*)d_in[19];
  const float* Wv3 = (const float*)d_in[20]; const float* bv3 = (const float*)d_in[21];
  const float* Wvs = (const float*)d_in[22]; const float* bvs = (const float*)d_in[23];
  const float* freq = (const float*)d_in[24];
  float* out = (float*)d_out;

  char* ws = (char*)d_ws;
  bf16_t* er     = (bf16_t*)(ws + 0);          // 8192*1024*2  = 16777216
  bf16_t* WpcT   = (bf16_t*)(ws + 16777216);   // 4096*1024*2  =  8388608
  bf16_t* WpeT   = (bf16_t*)(ws + 25165824);   // 1024*512*2   =  1048576
  bf16_t* WcatT  = (bf16_t*)(ws + 26214400);   // 64*4096*2    =   524288
  bf16_t* WvcatT = (bf16_t*)(ws + 26738688);   // 64*4096*2    =   524288
  float*  bcv    = (float*)(ws + 27262976);    // 64*4         =      256

  k_transpose<<<dim3(64, 16), 256, 0, stream>>>(Wpc, WpcT, 1024, 4096);
  k_transpose<<<dim3(16, 8), 256, 0, stream>>>(Wpe, WpeT, 512, 1024);
  k_pack_cat<<<64, 256, 0, stream>>>(Wc1, Wc2, Wc3, Wcs, Wv1, Wv2, Wv3, Wvs,
                                     bc1, bc2, bc3, bcs, bv1, bv2, bv3, bvs,
                                     WcatT, WvcatT, bcv);
  k_er<<<dim3(8, 64), 256, 0, stream>>>(edge_ctx, WpeT, bpe, er);
  k_main<<<256, 256, 0, stream>>>(er, WpcT, bpc, WcatT, WvcatT, bcv,
                                  pair_idx, pair_pred, vis_rep, freq, out);
}

// Round 2
// 384.079 us; speedup vs baseline: 2.9998x; 2.9998x over previous
//
#include <hip/hip_runtime.h>
#include <hip/hip_bf16.h>

typedef __bf16 bf16_t;
typedef __bf16 bf16x8 __attribute__((ext_vector_type(8)));
typedef __bf16 bf16x4 __attribute__((ext_vector_type(4)));
typedef float f32x4 __attribute__((ext_vector_type(4)));

#define DI __device__ __forceinline__

DI f32x4 mfma16(bf16x8 a, bf16x8 b, f32x4 c) {
  return __builtin_amdgcn_mfma_f32_16x16x32_bf16(a, b, c, 0, 0, 0);
}

__constant__ int GEO_c[15] = {1,2,3,4,5,6,8,10,22,23,29,31,32,33,43};
__constant__ int POS_c[11] = {9,16,17,20,27,30,36,42,48,49,50};
__constant__ int SEM_c[24] = {7,11,12,13,14,15,18,19,21,24,25,26,28,34,35,37,38,39,40,41,44,45,46,47};

// ---------- prep: transpose f32 [K][N] -> bf16 [N][K] ----------
__global__ void k_transpose(const float* __restrict__ src, bf16_t* __restrict__ dst,
                            int K, int N) {
  __shared__ float s[64][65];
  int n0 = blockIdx.x * 64, k0 = blockIdx.y * 64;
  int t = threadIdx.x;
#pragma unroll
  for (int i = 0; i < 4; ++i) {
    int idx = t + i * 256; int kr = idx >> 4, seg = idx & 15;
    float4 v = *(const float4*)(src + (size_t)(k0 + kr) * N + n0 + seg * 4);
    s[kr][seg * 4 + 0] = v.x; s[kr][seg * 4 + 1] = v.y;
    s[kr][seg * 4 + 2] = v.z; s[kr][seg * 4 + 3] = v.w;
  }
  __syncthreads();
#pragma unroll
  for (int i = 0; i < 4; ++i) {
    int idx = t + i * 256; int nr = idx >> 4, seg = idx & 15;
    bf16x4 h;
    h[0] = (bf16_t)s[seg * 4 + 0][nr]; h[1] = (bf16_t)s[seg * 4 + 1][nr];
    h[2] = (bf16_t)s[seg * 4 + 2][nr]; h[3] = (bf16_t)s[seg * 4 + 3][nr];
    *(bf16x4*)(dst + (size_t)(n0 + nr) * K + k0 + seg * 4) = h;
  }
}

// ---------- prep: pack Wc*/Wv* into [64][4096] bf16 (cols 54..63 zero), bcv ----------
DI void cat_map(int j, int& which, int& sub, int& nc) {
  if (j < 15)      { which = 0; sub = j;      nc = 15; }
  else if (j < 26) { which = 1; sub = j - 15; nc = 11; }
  else if (j < 50) { which = 2; sub = j - 26; nc = 24; }
  else if (j < 54) { which = 3; sub = j - 50; nc = 4;  }
  else             { which = 4; sub = 0;      nc = 1;  }
}

__global__ void k_pack_cat(const float* __restrict__ Wc1, const float* __restrict__ Wc2,
                           const float* __restrict__ Wc3, const float* __restrict__ Wcs,
                           const float* __restrict__ Wv1, const float* __restrict__ Wv2,
                           const float* __restrict__ Wv3, const float* __restrict__ Wvs,
                           const float* __restrict__ bc1, const float* __restrict__ bc2,
                           const float* __restrict__ bc3, const float* __restrict__ bcs,
                           const float* __restrict__ bv1, const float* __restrict__ bv2,
                           const float* __restrict__ bv3, const float* __restrict__ bvs,
                           bf16_t* __restrict__ WcatT, bf16_t* __restrict__ WvcatT,
                           float* __restrict__ bcv) {
  int j = blockIdx.x, t = threadIdx.x;
  int which, sub, nc; cat_map(j, which, sub, nc);
  const float* Wc = which == 0 ? Wc1 : which == 1 ? Wc2 : which == 2 ? Wc3 : Wcs;
  const float* Wv = which == 0 ? Wv1 : which == 1 ? Wv2 : which == 2 ? Wv3 : Wvs;
  for (int i = 0; i < 16; ++i) {
    int k = t + i * 256;
    float vc = 0.f, vv = 0.f;
    if (which < 4) { vc = Wc[(size_t)k * nc + sub]; vv = Wv[(size_t)k * nc + sub]; }
    WcatT[(size_t)j * 4096 + k] = (bf16_t)vc;
    WvcatT[(size_t)j * 4096 + k] = (bf16_t)vv;
  }
  if (t == 0) {
    float b = 0.f;
    if (which < 4) {
      const float* bc = which == 0 ? bc1 : which == 1 ? bc2 : which == 2 ? bc3 : bcs;
      const float* bv = which == 0 ? bv1 : which == 1 ? bv2 : which == 2 ? bv3 : bvs;
      b = bc[sub] + bv[sub];
    }
    bcv[j] = b;
  }
}

// ---------- er = edge_ctx @ W_post_emb + b  -> bf16 [8192][1024] ----------
__global__ __launch_bounds__(256) void k_er(const float* __restrict__ ec,
                                            const bf16_t* __restrict__ WpeT,
                                            const float* __restrict__ bpe,
                                            bf16_t* __restrict__ er) {
  __shared__ bf16_t sA[128 * 64];
  __shared__ bf16_t sB[128 * 64];
  const int m0 = blockIdx.y * 128, n0 = blockIdx.x * 128;
  const int t = threadIdx.x, w = t >> 6, l = t & 63;
  const int lrow = l & 15, lkB = (l >> 4) << 4;

  f32x4 acc[2][8];
#pragma unroll
  for (int rf = 0; rf < 2; ++rf)
#pragma unroll
    for (int cf = 0; cf < 8; ++cf) { f32x4 z = {0.f, 0.f, 0.f, 0.f}; acc[rf][cf] = z; }

  for (int kk = 0; kk < 512; kk += 64) {
    __syncthreads();
#pragma unroll
    for (int i = 0; i < 8; ++i) {
      int idx = t + i * 256; int row = idx >> 4, seg = idx & 15;
      float4 v = *(const float4*)(ec + (size_t)(m0 + row) * 512 + kk + seg * 4);
      bf16x4 h; h[0] = (bf16_t)v.x; h[1] = (bf16_t)v.y; h[2] = (bf16_t)v.z; h[3] = (bf16_t)v.w;
      *(bf16x4*)((char*)sA + (row << 7) + ((seg << 3) ^ ((row & 7) << 4))) = h;
    }
#pragma unroll
    for (int i = 0; i < 4; ++i) {
      int idx = t + i * 256; int col = idx >> 3, seg = idx & 7;
      bf16x8 v = *(const bf16x8*)(WpeT + (size_t)(n0 + col) * 512 + kk + seg * 8);
      *(bf16x8*)((char*)sB + (col << 7) + ((seg << 4) ^ ((col & 7) << 4))) = v;
    }
    __syncthreads();
#pragma unroll
    for (int ks = 0; ks < 2; ++ks) {
      bf16x8 af[2], bfr[8];
#pragma unroll
      for (int rf = 0; rf < 2; ++rf) {
        int row = w * 32 + rf * 16 + lrow;
        af[rf] = *(const bf16x8*)((const char*)sA + (row << 7) + (((ks << 6) | lkB) ^ ((row & 7) << 4)));
      }
#pragma unroll
      for (int cf = 0; cf < 8; ++cf) {
        int col = cf * 16 + lrow;
        bfr[cf] = *(const bf16x8*)((const char*)sB + (col << 7) + (((ks << 6) | lkB) ^ ((col & 7) << 4)));
      }
#pragma unroll
      for (int rf = 0; rf < 2; ++rf)
#pragma unroll
        for (int cf = 0; cf < 8; ++cf)
          acc[rf][cf] = mfma16(af[rf], bfr[cf], acc[rf][cf]);
    }
  }
#pragma unroll
  for (int cf = 0; cf < 8; ++cf) {
    float bias = bpe[n0 + cf * 16 + lrow];
#pragma unroll
    for (int rf = 0; rf < 2; ++rf)
#pragma unroll
      for (int r = 0; r < 4; ++r) {
        int row = m0 + w * 32 + rf * 16 + ((l >> 4) << 2) + r;
        er[(size_t)row * 1024 + n0 + cf * 16 + lrow] = (bf16_t)(acc[rf][cf][r] + bias);
      }
  }
}

// ---------- k_ht: HU = er[:, :512] @ WpcTop + bpc ; TU = er[:, 512:] @ WpcBot ----------
__global__ __launch_bounds__(256, 4) void k_ht(const bf16_t* __restrict__ er,
                                               const bf16_t* __restrict__ WpcT,
                                               const float* __restrict__ bpc,
                                               bf16_t* __restrict__ HU,
                                               bf16_t* __restrict__ TU) {
  __shared__ bf16_t sA[128 * 64];
  __shared__ bf16_t sB[128 * 64];
  const int t = threadIdx.x, w = t >> 6, l = t & 63;
  const int lrow = l & 15, lkB = (l >> 4) << 4;
  const int n0 = blockIdx.x * 128, m0 = blockIdx.y * 128;
  const int z = blockIdx.z;
  const int koff = z * 512;
  bf16_t* dst = z ? TU : HU;

  f32x4 acc[2][8];
#pragma unroll
  for (int rf = 0; rf < 2; ++rf)
#pragma unroll
    for (int cf = 0; cf < 8; ++cf) { f32x4 zz = {0.f, 0.f, 0.f, 0.f}; acc[rf][cf] = zz; }

#pragma unroll 1
  for (int kk = 0; kk < 512; kk += 64) {
    __syncthreads();
    const int aSeg = t & 7;
#pragma unroll
    for (int i = 0; i < 4; ++i) {
      int row = (t >> 3) + (i << 5);
      bf16x8 v = *(const bf16x8*)(er + (size_t)(m0 + row) * 1024 + koff + kk + aSeg * 8);
      *(bf16x8*)((char*)sA + (row << 7) + ((aSeg << 4) ^ ((row & 7) << 4))) = v;
    }
#pragma unroll
    for (int i = 0; i < 4; ++i) {
      int col = (t >> 3) + (i << 5);
      bf16x8 v = *(const bf16x8*)(WpcT + (size_t)(n0 + col) * 1024 + koff + kk + aSeg * 8);
      *(bf16x8*)((char*)sB + (col << 7) + ((aSeg << 4) ^ ((col & 7) << 4))) = v;
    }
    __syncthreads();
#pragma unroll
    for (int ks = 0; ks < 2; ++ks) {
      bf16x8 af[2], bfr[8];
#pragma unroll
      for (int rf = 0; rf < 2; ++rf) {
        int row = w * 32 + rf * 16 + lrow;
        af[rf] = *(const bf16x8*)((const char*)sA + (row << 7) + (((ks << 6) | lkB) ^ ((row & 7) << 4)));
      }
#pragma unroll
      for (int cf = 0; cf < 8; ++cf) {
        int col = cf * 16 + lrow;
        bfr[cf] = *(const bf16x8*)((const char*)sB + (col << 7) + (((ks << 6) | lkB) ^ ((col & 7) << 4)));
      }
#pragma unroll
      for (int rf = 0; rf < 2; ++rf)
#pragma unroll
        for (int cf = 0; cf < 8; ++cf)
          acc[rf][cf] = mfma16(af[rf], bfr[cf], acc[rf][cf]);
    }
  }
#pragma unroll
  for (int cf = 0; cf < 8; ++cf) {
    float bias = z ? 0.f : bpc[n0 + cf * 16 + lrow];
#pragma unroll
    for (int rf = 0; rf < 2; ++rf)
#pragma unroll
      for (int r = 0; r < 4; ++r) {
        int row = m0 + w * 32 + rf * 16 + ((l >> 4) << 2) + r;
        dst[(size_t)row * 4096 + n0 + cf * 16 + lrow] = (bf16_t)(acc[rf][cf][r] + bias);
      }
  }
}

// ---------- k_out: P = relu(HU[r0]+TU[r1]); out = P@Wcat + vis@Wvcat + freq epilogue ----------
DI void gemm_small(const bf16_t* sX, const bf16_t* sWl, f32x4 (&acc)[4],
                   int w, int lrow, int lkB) {
#pragma unroll
  for (int ks = 0; ks < 4; ++ks) {
    int row = w * 16 + lrow;
    bf16x8 af = *(const bf16x8*)((const char*)sX + (row << 8) + (((ks << 6) | lkB) ^ ((row & 7) << 4)));
    bf16x8 bfr[4];
#pragma unroll
    for (int cf = 0; cf < 4; ++cf) {
      int col = cf * 16 + lrow;
      bfr[cf] = *(const bf16x8*)((const char*)sWl + (col << 8) + (((ks << 6) | lkB) ^ ((col & 7) << 4)));
    }
#pragma unroll
    for (int cf = 0; cf < 4; ++cf)
      acc[cf] = mfma16(af, bfr[cf], acc[cf]);
  }
}

__global__ __launch_bounds__(256, 4) void k_out(
    const bf16_t* __restrict__ HU, const bf16_t* __restrict__ TU,
    const bf16_t* __restrict__ WcatT, const bf16_t* __restrict__ WvcatT,
    const float* __restrict__ bcv,
    const int* __restrict__ pair_idx, const int* __restrict__ pair_pred,
    const float* __restrict__ vis, const float* __restrict__ freq,
    float* __restrict__ out) {
  __shared__ char smem[32768];
  bf16_t* sX = (bf16_t*)smem;            // [64][128] bf16 swizzled
  bf16_t* sW = (bf16_t*)(smem + 16384);  // [64][128] bf16 swizzled
  __shared__ int sR0[64], sR1[64];

  const int t = threadIdx.x, w = t >> 6, l = t & 63;
  const int lrow = l & 15, lkB = (l >> 4) << 4;
  const int p0 = blockIdx.x * 64;

  if (t < 64) { sR0[t] = pair_idx[(p0 + t) * 2]; sR1[t] = pair_idx[(p0 + t) * 2 + 1]; }
  f32x4 acc[4];
#pragma unroll
  for (int cf = 0; cf < 4; ++cf) { f32x4 z = {0.f, 0.f, 0.f, 0.f}; acc[cf] = z; }

  const int srow = t >> 2, sseg = t & 3;   // staging: 4 threads/row, 32 cols each
  __syncthreads();
  const int hr = sR0[srow], tr = sR1[srow];
  const bf16_t* hbase = HU + (size_t)hr * 4096 + sseg * 32;
  const bf16_t* tbase = TU + (size_t)tr * 4096 + sseg * 32;
  const bf16_t* vbase0 = (const bf16_t*)(vis + (size_t)(p0 + srow) * 4096 + sseg * 32);
  const bf16_t* wc = WcatT + (size_t)srow * 4096 + sseg * 32;
  const bf16_t* wv = WvcatT + (size_t)srow * 4096 + sseg * 32;

#pragma unroll 1
  for (int nc = 0; nc < 32; ++nc) {
    const int nbase = nc * 128;
    // stage P = relu(HU[hr]+TU[tr])
#pragma unroll
    for (int j = 0; j < 4; ++j) {
      bf16x8 hv = *(const bf16x8*)(hbase + nbase + j * 8);
      bf16x8 tv = *(const bf16x8*)(tbase + nbase + j * 8);
      bf16x8 pv;
#pragma unroll
      for (int e = 0; e < 8; ++e)
        pv[e] = (bf16_t)fmaxf((float)hv[e] + (float)tv[e], 0.f);
      int c = sseg * 32 + j * 8;
      *(bf16x8*)((char*)sX + (srow << 8) + ((c << 1) ^ ((srow & 7) << 4))) = pv;
    }
    // stage Wcat
#pragma unroll
    for (int j = 0; j < 4; ++j) {
      bf16x8 v = *(const bf16x8*)(wc + nbase + j * 8);
      int c = sseg * 32 + j * 8;
      *(bf16x8*)((char*)sW + (srow << 8) + ((c << 1) ^ ((srow & 7) << 4))) = v;
    }
    __syncthreads();
    gemm_small(sX, sW, acc, w, lrow, lkB);
    __syncthreads();
    // stage vis (f32 -> bf16)
    const float* vp = (const float*)vbase0 + nbase;
#pragma unroll
    for (int j = 0; j < 8; ++j) {
      float4 v = *(const float4*)(vp + j * 4);
      bf16x4 h; h[0] = (bf16_t)v.x; h[1] = (bf16_t)v.y; h[2] = (bf16_t)v.z; h[3] = (bf16_t)v.w;
      int c = sseg * 32 + j * 4;
      *(bf16x4*)((char*)sX + (srow << 8) + ((c << 1) ^ ((srow & 7) << 4))) = h;
    }
    // stage Wvcat
#pragma unroll
    for (int j = 0; j < 4; ++j) {
      bf16x8 v = *(const bf16x8*)(wv + nbase + j * 8);
      int c = sseg * 32 + j * 8;
      *(bf16x8*)((char*)sW + (srow << 8) + ((c << 1) ^ ((srow & 7) << 4))) = v;
    }
    __syncthreads();
    gemm_small(sX, sW, acc, w, lrow, lkB);
    __syncthreads();
  }

  // epilogue
  float* sF = (float*)smem;  // [64][65] f32
#pragma unroll
  for (int cf = 0; cf < 4; ++cf) {
    float bb = bcv[cf * 16 + lrow];
#pragma unroll
    for (int r = 0; r < 4; ++r) {
      int row = w * 16 + ((l >> 4) << 2) + r;
      sF[row * 65 + cf * 16 + lrow] = acc[cf][r] + bb;
    }
  }
  __syncthreads();
  if (t < 64) {
    int p = p0 + t;
    const float* f = freq + ((size_t)pair_pred[p * 2] * 151 + pair_pred[p * 2 + 1]) * 51;
    const float* rowv = sF + t * 65;
    float e1 = 0.f, e2 = 0.f, e3 = 0.f;
#pragma unroll
    for (int c = 0; c < 15; ++c) {
      float fb = f[GEO_c[c]]; e1 += expf(fb);
      out[(size_t)p * 15 + c] = rowv[c] + fb;
    }
#pragma unroll
    for (int c = 0; c < 11; ++c) {
      float fb = f[POS_c[c]]; e2 += expf(fb);
      out[491520 + (size_t)p * 11 + c] = rowv[15 + c] + fb;
    }
#pragma unroll
    for (int c = 0; c < 24; ++c) {
      float fb = f[SEM_c[c]]; e3 += expf(fb);
      out[851968 + (size_t)p * 24 + c] = rowv[26 + c] + fb;
    }
    out[1638400 + (size_t)p * 4 + 0] = rowv[50] + f[0];
    out[1638400 + (size_t)p * 4 + 1] = rowv[51] + logf(e1);
    out[1638400 + (size_t)p * 4 + 2] = rowv[52] + logf(e2);
    out[1638400 + (size_t)p * 4 + 3] = rowv[53] + logf(e3);
  }
}

// ---------- fallback fused kernel (round-1, used if ws too small) ----------
DI void gemm2(const bf16_t* sP, const bf16_t* sWl, f32x4 (&acc)[2][4],
              int w, int lrow, int lkB) {
#pragma unroll
  for (int ks = 0; ks < 4; ++ks) {
    bf16x8 af[2], bfr[4];
#pragma unroll
    for (int rf = 0; rf < 2; ++rf) {
      int row = w * 32 + rf * 16 + lrow;
      af[rf] = *(const bf16x8*)((const char*)sP + (row << 8) + (((ks << 6) | lkB) ^ ((row & 7) << 4)));
    }
#pragma unroll
    for (int cf = 0; cf < 4; ++cf) {
      int col = cf * 16 + lrow;
      bfr[cf] = *(const bf16x8*)((const char*)sWl + (col << 8) + (((ks << 6) | lkB) ^ ((col & 7) << 4)));
    }
#pragma unroll
    for (int rf = 0; rf < 2; ++rf)
#pragma unroll
      for (int cf = 0; cf < 4; ++cf)
        acc[rf][cf] = mfma16(af[rf], bfr[cf], acc[rf][cf]);
  }
}

__global__ __launch_bounds__(256, 2) void k_main(
    const bf16_t* __restrict__ er, const bf16_t* __restrict__ WpcT,
    const float* __restrict__ bpc,
    const bf16_t* __restrict__ WcatT, const bf16_t* __restrict__ WvcatT,
    const float* __restrict__ bcv,
    const int* __restrict__ pair_idx, const int* __restrict__ pair_pred,
    const float* __restrict__ vis, const float* __restrict__ freq,
    float* __restrict__ out) {
  __shared__ bf16_t sA[128 * 64];
  __shared__ bf16_t sB[128 * 64];
  __shared__ bf16_t sPV[128 * 128];
  __shared__ bf16_t sW[64 * 128];

  const int t = threadIdx.x;
  const int w = t >> 6, l = t & 63;
  const int lrow = l & 15;
  const int lkB = (l >> 4) << 4;
  const int p0 = blockIdx.x * 128;

  int r0[4], r1[4];
#pragma unroll
  for (int i = 0; i < 4; ++i) {
    int prow = p0 + (t >> 3) + (i << 5);
    r0[i] = pair_idx[prow * 2];
    r1[i] = pair_idx[prow * 2 + 1];
  }

  f32x4 acc[2][4];
#pragma unroll
  for (int rf = 0; rf < 2; ++rf)
#pragma unroll
    for (int cf = 0; cf < 4; ++cf) { f32x4 z = {0.f, 0.f, 0.f, 0.f}; acc[rf][cf] = z; }

#pragma unroll 1
  for (int nc = 0; nc < 32; ++nc) {
    const size_t nbase = (size_t)nc * 128;
    f32x4 pacc[2][8];
#pragma unroll
    for (int rf = 0; rf < 2; ++rf)
#pragma unroll
      for (int cf = 0; cf < 8; ++cf) { f32x4 z = {0.f, 0.f, 0.f, 0.f}; pacc[rf][cf] = z; }

#pragma unroll 1
    for (int kk = 0; kk < 1024; kk += 64) {
      __syncthreads();
      const int aSeg = t & 7;
#pragma unroll
      for (int i = 0; i < 4; ++i) {
        int row = (t >> 3) + (i << 5);
        int sr = (kk < 512) ? r0[i] : r1[i];
        bf16x8 v = *(const bf16x8*)(er + (size_t)sr * 1024 + kk + aSeg * 8);
        *(bf16x8*)((char*)sA + (row << 7) + ((aSeg << 4) ^ ((row & 7) << 4))) = v;
      }
#pragma unroll
      for (int i = 0; i < 4; ++i) {
        int col = (t >> 3) + (i << 5);
        bf16x8 v = *(const bf16x8*)(WpcT + (nbase + col) * 1024 + kk + aSeg * 8);
        *(bf16x8*)((char*)sB + (col << 7) + ((aSeg << 4) ^ ((col & 7) << 4))) = v;
      }
      __syncthreads();
#pragma unroll
      for (int ks = 0; ks < 2; ++ks) {
        bf16x8 af[2], bfr[8];
#pragma unroll
        for (int rf = 0; rf < 2; ++rf) {
          int row = w * 32 + rf * 16 + lrow;
          af[rf] = *(const bf16x8*)((const char*)sA + (row << 7) + (((ks << 6) | lkB) ^ ((row & 7) << 4)));
        }
#pragma unroll
        for (int cf = 0; cf < 8; ++cf) {
          int col = cf * 16 + lrow;
          bfr[cf] = *(const bf16x8*)((const char*)sB + (col << 7) + (((ks << 6) | lkB) ^ ((col & 7) << 4)));
        }
#pragma unroll
        for (int rf = 0; rf < 2; ++rf)
#pragma unroll
          for (int cf = 0; cf < 8; ++cf)
            pacc[rf][cf] = mfma16(af[rf], bfr[cf], pacc[rf][cf]);
      }
    }

#pragma unroll
    for (int cf = 0; cf < 8; ++cf) {
      float bias = bpc[nbase + cf * 16 + lrow];
#pragma unroll
      for (int rf = 0; rf < 2; ++rf)
#pragma unroll
        for (int r = 0; r < 4; ++r) {
          int row = w * 32 + rf * 16 + ((l >> 4) << 2) + r;
          float x = fmaxf(pacc[rf][cf][r] + bias, 0.f);
          *(bf16_t*)((char*)sPV + (row << 8) + (((cf * 16 + lrow) << 1) ^ ((row & 7) << 4))) = (bf16_t)x;
        }
    }
#pragma unroll
    for (int i = 0; i < 4; ++i) {
      int j = (t >> 4) + (i << 4), seg = t & 15;
      bf16x8 v = *(const bf16x8*)(WcatT + (size_t)j * 4096 + nbase + seg * 8);
      *(bf16x8*)((char*)sW + (j << 8) + ((seg << 4) ^ ((j & 7) << 4))) = v;
    }
    __syncthreads();
    gemm2(sPV, sW, acc, w, lrow, lkB);
    __syncthreads();
#pragma unroll
    for (int i = 0; i < 16; ++i) {
      int row = (t >> 5) + (i << 3), seg = t & 31;
      float4 v = *(const float4*)(vis + (size_t)(p0 + row) * 4096 + nbase + seg * 4);
      bf16x4 h; h[0] = (bf16_t)v.x; h[1] = (bf16_t)v.y; h[2] = (bf16_t)v.z; h[3] = (bf16_t)v.w;
      *(bf16x4*)((char*)sPV + (row << 8) + ((seg << 3) ^ ((row & 7) << 4))) = h;
    }
#pragma unroll
    for (int i = 0; i < 4; ++i) {
      int j = (t >> 4) + (i << 4), seg = t & 15;
      bf16x8 v = *(const bf16x8*)(WvcatT + (size_t)j * 4096 + nbase + seg * 8);
      *(bf16x8*)((char*)sW + (j << 8) + ((seg << 4) ^ ((j & 7) << 4))) = v;
    }
    __syncthreads();
    gemm2(sPV, sW, acc, w, lrow, lkB);
  }

  __syncthreads();
  float* sF = (float*)sPV;
#pragma unroll
  for (int cf = 0; cf < 4; ++cf) {
    float bb = bcv[cf * 16 + lrow];
#pragma unroll
    for (int rf = 0; rf < 2; ++rf)
#pragma unroll
      for (int r = 0; r < 4; ++r) {
        int row = w * 32 + rf * 16 + ((l >> 4) << 2) + r;
        sF[row * 64 + cf * 16 + lrow] = acc[rf][cf][r] + bb;
      }
  }
  __syncthreads();
  if (t < 128) {
    int p = p0 + t;
    const float* f = freq + ((size_t)pair_pred[p * 2] * 151 + pair_pred[p * 2 + 1]) * 51;
    const float* rowv = sF + t * 64;
    float e1 = 0.f, e2 = 0.f, e3 = 0.f;
#pragma unroll
    for (int c = 0; c < 15; ++c) {
      float fb = f[GEO_c[c]]; e1 += expf(fb);
      out[(size_t)p * 15 + c] = rowv[c] + fb;
    }
#pragma unroll
    for (int c = 0; c < 11; ++c) {
      float fb = f[POS_c[c]]; e2 += expf(fb);
      out[491520 + (size_t)p * 11 + c] = rowv[15 + c] + fb;
    }
#pragma unroll
    for (int c = 0; c < 24; ++c) {
      float fb = f[SEM_c[c]]; e3 += expf(fb);
      out[851968 + (size_t)p * 24 + c] = rowv[26 + c] + fb;
    }
    out[1638400 + (size_t)p * 4 + 0] = rowv[50] + f[0];
    out[1638400 + (size_t)p * 4 + 1] = rowv[51] + logf(e1);
    out[1638400 + (size_t)p * 4 + 2] = rowv[52] + logf(e2);
    out[1638400 + (size_t)p * 4 + 3] = rowv[53] + logf(e3);
  }
}

extern "C" void kernel_launch(void* const* d_in, const int* in_sizes, int n_in,
                              void* d_out, int out_size, void* d_ws, size_t ws_size,
                              hipStream_t stream) {
  const float* edge_ctx  = (const float*)d_in[0];
  const int*   pair_idx  = (const int*)d_in[1];
  const float* vis_rep   = (const float*)d_in[2];
  const int*   pair_pred = (const int*)d_in[3];
  const float* Wpe = (const float*)d_in[4];
  const float* bpe = (const float*)d_in[5];
  const float* Wpc = (const float*)d_in[6];
  const float* bpc = (const float*)d_in[7];
  const float* Wc1 = (const float*)d_in[8];  const float* bc1 = (const float*)d_in[9];
  const float* Wc2 = (const float*)d_in[10]; const float* bc2 = (const float*)d_in[11];
  const float* Wc3 = (const float*)d_in[12]; const float* bc3 = (const float*)d_in[13];
  const float* Wcs = (const float*)d_in[14]; const float* bcs = (const float*)d_in[15];
  const float* Wv1 = (const float*)d_in[16]; const float* bv1 = (const float*)d_in[17];
  const float* Wv2 = (const float*)d_in[18]; const float* bv2 = (const float*)d_in[19];
  const float* Wv3 = (const float*)d_in[20]; const float* bv3 = (const float*)d_in[21];
  const float* Wvs = (const float*)d_in[22]; const float* bvs = (const float*)d_in[23];
  const float* freq = (const float*)d_in[24];
  float* out = (float*)d_out;

  char* ws = (char*)d_ws;
  bf16_t* er     = (bf16_t*)(ws + 0);          // 16777216
  bf16_t* WpcT   = (bf16_t*)(ws + 16777216);   //  8388608
  bf16_t* WpeT   = (bf16_t*)(ws + 25165824);   //  1048576
  bf16_t* WcatT  = (bf16_t*)(ws + 26214400);   //   524288
  bf16_t* WvcatT = (bf16_t*)(ws + 26738688);   //   524288
  float*  bcv    = (float*)(ws + 27262976);    //      256
  bf16_t* HU     = (bf16_t*)(ws + 29360128);   // 67108864
  bf16_t* TU     = (bf16_t*)(ws + 96468992);   // 67108864
  const size_t need = 163577856ULL;

  k_transpose<<<dim3(64, 16), 256, 0, stream>>>(Wpc, WpcT, 1024, 4096);
  k_transpose<<<dim3(16, 8), 256, 0, stream>>>(Wpe, WpeT, 512, 1024);
  k_pack_cat<<<64, 256, 0, stream>>>(Wc1, Wc2, Wc3, Wcs, Wv1, Wv2, Wv3, Wvs,
                                     bc1, bc2, bc3, bcs, bv1, bv2, bv3, bvs,
                                     WcatT, WvcatT, bcv);
  k_er<<<dim3(8, 64), 256, 0, stream>>>(edge_ctx, WpeT, bpe, er);

  if (ws_size >= need) {
    k_ht<<<dim3(32, 64, 2), 256, 0, stream>>>(er, WpcT, bpc, HU, TU);
    k_out<<<512, 256, 0, stream>>>(HU, TU, WcatT, WvcatT, bcv,
                                   pair_idx, pair_pred, vis_rep, freq, out);
  } else {
    k_main<<<256, 256, 0, stream>>>(er, WpcT, bpc, WcatT, WvcatT, bcv,
                                    pair_idx, pair_pred, vis_rep, freq, out);
  }
}

// Round 3
// 359.794 us; speedup vs baseline: 3.2022x; 1.0675x over previous
//
#include <hip/hip_runtime.h>
#include <hip/hip_bf16.h>

typedef __bf16 bf16_t;
typedef __bf16 bf16x8 __attribute__((ext_vector_type(8)));
typedef __bf16 bf16x4 __attribute__((ext_vector_type(4)));
typedef float f32x4 __attribute__((ext_vector_type(4)));

#define DI __device__ __forceinline__

DI f32x4 mfma16(bf16x8 a, bf16x8 b, f32x4 c) {
  return __builtin_amdgcn_mfma_f32_16x16x32_bf16(a, b, c, 0, 0, 0);
}

DI void gload16(const bf16_t* g, bf16_t* l) {
  __builtin_amdgcn_global_load_lds(
      (const __attribute__((address_space(1))) unsigned int*)g,
      (__attribute__((address_space(3))) unsigned int*)l, 16, 0, 0);
}

__constant__ int GEO_c[15] = {1,2,3,4,5,6,8,10,22,23,29,31,32,33,43};
__constant__ int POS_c[11] = {9,16,17,20,27,30,36,42,48,49,50};
__constant__ int SEM_c[24] = {7,11,12,13,14,15,18,19,21,24,25,26,28,34,35,37,38,39,40,41,44,45,46,47};

// ---------- prep: transpose f32 Wpc [1024][4096] -> bf16 WpcT [4096][1024] ----------
__global__ void k_transpose(const float* __restrict__ src, bf16_t* __restrict__ dst,
                            int K, int N) {
  __shared__ float s[64][65];
  int n0 = blockIdx.x * 64, k0 = blockIdx.y * 64;
  int t = threadIdx.x;
#pragma unroll
  for (int i = 0; i < 4; ++i) {
    int idx = t + i * 256; int kr = idx >> 4, seg = idx & 15;
    float4 v = *(const float4*)(src + (size_t)(k0 + kr) * N + n0 + seg * 4);
    s[kr][seg * 4 + 0] = v.x; s[kr][seg * 4 + 1] = v.y;
    s[kr][seg * 4 + 2] = v.z; s[kr][seg * 4 + 3] = v.w;
  }
  __syncthreads();
#pragma unroll
  for (int i = 0; i < 4; ++i) {
    int idx = t + i * 256; int nr = idx >> 4, seg = idx & 15;
    bf16x4 h;
    h[0] = (bf16_t)s[seg * 4 + 0][nr]; h[1] = (bf16_t)s[seg * 4 + 1][nr];
    h[2] = (bf16_t)s[seg * 4 + 2][nr]; h[3] = (bf16_t)s[seg * 4 + 3][nr];
    *(bf16x4*)(dst + (size_t)(n0 + nr) * K + k0 + seg * 4) = h;
  }
}

// ---------- prep: pack Wc*/Wv* into [64][4096] bf16 (cols 54..63 zero), bcv ----------
DI void cat_map(int j, int& which, int& sub, int& nc) {
  if (j < 15)      { which = 0; sub = j;      nc = 15; }
  else if (j < 26) { which = 1; sub = j - 15; nc = 11; }
  else if (j < 50) { which = 2; sub = j - 26; nc = 24; }
  else if (j < 54) { which = 3; sub = j - 50; nc = 4;  }
  else             { which = 4; sub = 0;      nc = 1;  }
}

__global__ void k_pack_cat(const float* __restrict__ Wc1, const float* __restrict__ Wc2,
                           const float* __restrict__ Wc3, const float* __restrict__ Wcs,
                           const float* __restrict__ Wv1, const float* __restrict__ Wv2,
                           const float* __restrict__ Wv3, const float* __restrict__ Wvs,
                           const float* __restrict__ bc1, const float* __restrict__ bc2,
                           const float* __restrict__ bc3, const float* __restrict__ bcs,
                           const float* __restrict__ bv1, const float* __restrict__ bv2,
                           const float* __restrict__ bv3, const float* __restrict__ bvs,
                           bf16_t* __restrict__ WcatT, bf16_t* __restrict__ WvcatT,
                           float* __restrict__ bcv) {
  int j = blockIdx.x, t = threadIdx.x;
  int which, sub, nc; cat_map(j, which, sub, nc);
  const float* Wc = which == 0 ? Wc1 : which == 1 ? Wc2 : which == 2 ? Wc3 : Wcs;
  const float* Wv = which == 0 ? Wv1 : which == 1 ? Wv2 : which == 2 ? Wv3 : Wvs;
  for (int i = 0; i < 16; ++i) {
    int k = t + i * 256;
    float vc = 0.f, vv = 0.f;
    if (which < 4) { vc = Wc[(size_t)k * nc + sub]; vv = Wv[(size_t)k * nc + sub]; }
    WcatT[(size_t)j * 4096 + k] = (bf16_t)vc;
    WvcatT[(size_t)j * 4096 + k] = (bf16_t)vv;
  }
  if (t == 0) {
    float b = 0.f;
    if (which < 4) {
      const float* bc = which == 0 ? bc1 : which == 1 ? bc2 : which == 2 ? bc3 : bcs;
      const float* bv = which == 0 ? bv1 : which == 1 ? bv2 : which == 2 ? bv3 : bvs;
      b = bc[sub] + bv[sub];
    }
    bcv[j] = b;
  }
}

// ---------- prep: ec f32 -> ecb bf16 ----------
__global__ __launch_bounds__(256) void k_ec(const float* __restrict__ ec,
                                            bf16_t* __restrict__ ecb) {
  size_t i = ((size_t)blockIdx.x * 256 + threadIdx.x) * 8;
  float4 a = *(const float4*)(ec + i), b = *(const float4*)(ec + i + 4);
  bf16x8 h;
  h[0] = (bf16_t)a.x; h[1] = (bf16_t)a.y; h[2] = (bf16_t)a.z; h[3] = (bf16_t)a.w;
  h[4] = (bf16_t)b.x; h[5] = (bf16_t)b.y; h[6] = (bf16_t)b.z; h[7] = (bf16_t)b.w;
  *(bf16x8*)(ecb + i) = h;
}

// ---------- prep: W1T[n][k] = sum_j WpcT[n, joff+j] * Wpe[k, joff+j] ----------
__global__ __launch_bounds__(256) void k_w12(const bf16_t* __restrict__ WpcT,
                                             const float* __restrict__ Wpe,
                                             bf16_t* __restrict__ W1T,
                                             bf16_t* __restrict__ W2T) {
  __shared__ bf16_t sA[128 * 64];
  __shared__ bf16_t sB[128 * 64];
  const int t = threadIdx.x, w = t >> 6, l = t & 63;
  const int lrow = l & 15, lkB = (l >> 4) << 4;
  const int k0 = blockIdx.x * 128, n0 = blockIdx.y * 128;
  const int joff = blockIdx.z * 512;
  bf16_t* dst = blockIdx.z ? W2T : W1T;

  f32x4 acc[2][8];
#pragma unroll
  for (int rf = 0; rf < 2; ++rf)
#pragma unroll
    for (int cf = 0; cf < 8; ++cf) { f32x4 z = {0.f, 0.f, 0.f, 0.f}; acc[rf][cf] = z; }

  for (int jj = 0; jj < 512; jj += 64) {
    __syncthreads();
#pragma unroll
    for (int i = 0; i < 4; ++i) {
      int row = (t >> 3) + (i << 5), seg = t & 7;
      bf16x8 v = *(const bf16x8*)(WpcT + (size_t)(n0 + row) * 1024 + joff + jj + seg * 8);
      *(bf16x8*)((char*)sA + (row << 7) + ((seg << 4) ^ ((row & 7) << 4))) = v;
    }
#pragma unroll
    for (int i = 0; i < 8; ++i) {
      int idx = t + i * 256; int row = idx >> 4, seg = idx & 15;
      float4 v = *(const float4*)(Wpe + (size_t)(k0 + row) * 1024 + joff + jj + seg * 4);
      bf16x4 h; h[0] = (bf16_t)v.x; h[1] = (bf16_t)v.y; h[2] = (bf16_t)v.z; h[3] = (bf16_t)v.w;
      *(bf16x4*)((char*)sB + (row << 7) + ((seg << 3) ^ ((row & 7) << 4))) = h;
    }
    __syncthreads();
#pragma unroll
    for (int ks = 0; ks < 2; ++ks) {
      bf16x8 af[2], bfr[8];
#pragma unroll
      for (int rf = 0; rf < 2; ++rf) {
        int row = w * 32 + rf * 16 + lrow;
        af[rf] = *(const bf16x8*)((const char*)sA + (row << 7) + (((ks << 6) | lkB) ^ ((row & 7) << 4)));
      }
#pragma unroll
      for (int cf = 0; cf < 8; ++cf) {
        int col = cf * 16 + lrow;
        bfr[cf] = *(const bf16x8*)((const char*)sB + (col << 7) + (((ks << 6) | lkB) ^ ((col & 7) << 4)));
      }
#pragma unroll
      for (int rf = 0; rf < 2; ++rf)
#pragma unroll
        for (int cf = 0; cf < 8; ++cf)
          acc[rf][cf] = mfma16(af[rf], bfr[cf], acc[rf][cf]);
    }
  }
#pragma unroll
  for (int cf = 0; cf < 8; ++cf)
#pragma unroll
    for (int rf = 0; rf < 2; ++rf)
#pragma unroll
      for (int r = 0; r < 4; ++r) {
        int nrow = n0 + w * 32 + rf * 16 + ((l >> 4) << 2) + r;
        dst[(size_t)nrow * 512 + k0 + cf * 16 + lrow] = (bf16_t)acc[rf][cf][r];
      }
}

// ---------- prep: b12[0][n] = bpe_h . WpcT[n,:512] + bpc[n]; b12[1][n] = bpe_t . WpcT[n,512:] ----------
__global__ __launch_bounds__(256) void k_bias(const bf16_t* __restrict__ WpcT,
                                              const float* __restrict__ bpe,
                                              const float* __restrict__ bpc,
                                              float* __restrict__ b12) {
  int w = threadIdx.x >> 6, l = threadIdx.x & 63;
  int n = blockIdx.x * 4 + w;
  const bf16_t* r = WpcT + (size_t)n * 1024;
  bf16x8 v1 = *(const bf16x8*)(r + l * 8);
  bf16x8 v2 = *(const bf16x8*)(r + 512 + l * 8);
  float s1 = 0.f, s2 = 0.f;
#pragma unroll
  for (int e = 0; e < 8; ++e) {
    s1 += (float)v1[e] * bpe[l * 8 + e];
    s2 += (float)v2[e] * bpe[512 + l * 8 + e];
  }
#pragma unroll
  for (int off = 32; off; off >>= 1) {
    s1 += __shfl_down(s1, off);
    s2 += __shfl_down(s2, off);
  }
  if (l == 0) { b12[n] = s1 + bpc[n]; b12[4096 + n] = s2; }
}

// ---------- k_ht2: HU/TU = ecb @ W{1,2}T + b12 (m97-style: global_load_lds, linear LDS) ----------
__global__ __launch_bounds__(256, 4) void k_ht2(const bf16_t* __restrict__ ecb,
                                                const bf16_t* __restrict__ W1T,
                                                const bf16_t* __restrict__ W2T,
                                                const float* __restrict__ b12,
                                                bf16_t* __restrict__ HU,
                                                bf16_t* __restrict__ TU) {
  __shared__ bf16_t sA[128 * 64];
  __shared__ bf16_t sB[128 * 64];
  const int t = threadIdx.x, w = t >> 6, l = t & 63;
  const int lrow = l & 15, lkB = (l >> 4) << 4;
  const int n0 = blockIdx.x * 128, m0 = blockIdx.y * 128, z = blockIdx.z;
  const bf16_t* Bw = z ? W2T : W1T;
  const float* bias = b12 + z * 4096;
  bf16_t* dst = z ? TU : HU;

  const int srow = (w << 5) + (l >> 3);   // +8 per issue
  const int sk = (l & 7) * 8;             // element offset within 64-k chunk
  const bf16_t* gA = ecb + (size_t)(m0 + srow) * 512 + sk;
  const bf16_t* gB = Bw + (size_t)(n0 + srow) * 512 + sk;
  bf16_t* lA = sA + (w << 11);
  bf16_t* lB = sB + (w << 11);

  f32x4 acc[2][8];
#pragma unroll
  for (int rf = 0; rf < 2; ++rf)
#pragma unroll
    for (int cf = 0; cf < 8; ++cf) { f32x4 zz = {0.f, 0.f, 0.f, 0.f}; acc[rf][cf] = zz; }

#pragma unroll 1
  for (int kk = 0; kk < 512; kk += 64) {
    __syncthreads();
#pragma unroll
    for (int i = 0; i < 4; ++i) gload16(gA + i * 4096 + kk, lA + i * 512);
#pragma unroll
    for (int i = 0; i < 4; ++i) gload16(gB + i * 4096 + kk, lB + i * 512);
    asm volatile("s_waitcnt vmcnt(0)" ::: "memory");
    __syncthreads();
#pragma unroll
    for (int ks = 0; ks < 2; ++ks) {
      bf16x8 af[2], bfr[8];
#pragma unroll
      for (int rf = 0; rf < 2; ++rf) {
        int row = w * 32 + rf * 16 + lrow;
        af[rf] = *(const bf16x8*)((const char*)sA + (row << 7) + (ks << 6) + lkB);
      }
#pragma unroll
      for (int cf = 0; cf < 8; ++cf) {
        int col = cf * 16 + lrow;
        bfr[cf] = *(const bf16x8*)((const char*)sB + (col << 7) + (ks << 6) + lkB);
      }
#pragma unroll
      for (int rf = 0; rf < 2; ++rf)
#pragma unroll
        for (int cf = 0; cf < 8; ++cf)
          acc[rf][cf] = mfma16(af[rf], bfr[cf], acc[rf][cf]);
    }
  }
#pragma unroll
  for (int cf = 0; cf < 8; ++cf) {
    float bb = bias[n0 + cf * 16 + lrow];
#pragma unroll
    for (int rf = 0; rf < 2; ++rf)
#pragma unroll
      for (int r = 0; r < 4; ++r) {
        int row = m0 + w * 32 + rf * 16 + ((l >> 4) << 2) + r;
        dst[(size_t)row * 4096 + n0 + cf * 16 + lrow] = (bf16_t)(acc[rf][cf][r] + bb);
      }
  }
}

// ---------- k_out2: split-K partial of P@Wcat + vis@Wvcat ----------
DI void gemm_small(const bf16_t* sX, const bf16_t* sWl, f32x4 (&acc)[4],
                   int w, int lrow, int lkB) {
#pragma unroll
  for (int ks = 0; ks < 4; ++ks) {
    int row = w * 16 + lrow;
    bf16x8 af = *(const bf16x8*)((const char*)sX + (row << 8) + (((ks << 6) | lkB) ^ ((row & 7) << 4)));
    bf16x8 bfr[4];
#pragma unroll
    for (int cf = 0; cf < 4; ++cf) {
      int col = cf * 16 + lrow;
      bfr[cf] = *(const bf16x8*)((const char*)sWl + (col << 8) + (((ks << 6) | lkB) ^ ((col & 7) << 4)));
    }
#pragma unroll
    for (int cf = 0; cf < 4; ++cf)
      acc[cf] = mfma16(af, bfr[cf], acc[cf]);
  }
}

__global__ __launch_bounds__(256, 2) void k_out2(
    const bf16_t* __restrict__ HU, const bf16_t* __restrict__ TU,
    const bf16_t* __restrict__ WcatT, const bf16_t* __restrict__ WvcatT,
    const int* __restrict__ pair_idx, const float* __restrict__ vis,
    float* __restrict__ pacc) {
  __shared__ char smem[32768];
  bf16_t* sX = (bf16_t*)smem;            // [64][128] bf16 swizzled
  bf16_t* sW = (bf16_t*)(smem + 16384);
  __shared__ int sR0[64], sR1[64];

  const int t = threadIdx.x, w = t >> 6, l = t & 63;
  const int lrow = l & 15, lkB = (l >> 4) << 4;
  const int p0 = blockIdx.x * 64;
  const int ncb = blockIdx.y * 16;

  if (t < 64) { sR0[t] = pair_idx[(p0 + t) * 2]; sR1[t] = pair_idx[(p0 + t) * 2 + 1]; }
  f32x4 acc[4];
#pragma unroll
  for (int cf = 0; cf < 4; ++cf) { f32x4 z = {0.f, 0.f, 0.f, 0.f}; acc[cf] = z; }

  const int srow = t >> 2, sseg = t & 3;
  __syncthreads();
  const bf16_t* hbase = HU + (size_t)sR0[srow] * 4096 + sseg * 32;
  const bf16_t* tbase = TU + (size_t)sR1[srow] * 4096 + sseg * 32;
  const float* vp = vis + (size_t)(p0 + srow) * 4096 + sseg * 32;
  const bf16_t* wcp = WcatT + (size_t)srow * 4096 + sseg * 32;
  const bf16_t* wvp = WvcatT + (size_t)srow * 4096 + sseg * 32;

  bf16x8 hv[4], tv[4], wc[4], wvv[4]; float4 vv[8];
  {
    const int nb = ncb * 128;
#pragma unroll
    for (int j = 0; j < 4; ++j) {
      hv[j] = *(const bf16x8*)(hbase + nb + j * 8);
      tv[j] = *(const bf16x8*)(tbase + nb + j * 8);
      wc[j] = *(const bf16x8*)(wcp + nb + j * 8);
    }
  }
#pragma unroll 1
  for (int i = 0; i < 16; ++i) {
    const int nb = (ncb + i) * 128;
    __syncthreads();                       // prev gemm2 done
#pragma unroll
    for (int j = 0; j < 4; ++j) {
      bf16x8 pv;
#pragma unroll
      for (int e = 0; e < 8; ++e)
        pv[e] = (bf16_t)fmaxf((float)hv[j][e] + (float)tv[j][e], 0.f);
      int c = sseg * 32 + j * 8;
      *(bf16x8*)((char*)sX + (srow << 8) + ((c << 1) ^ ((srow & 7) << 4))) = pv;
      *(bf16x8*)((char*)sW + (srow << 8) + ((c << 1) ^ ((srow & 7) << 4))) = wc[j];
    }
    // prefetch vis/Wvcat for this chunk (used after gemm1)
#pragma unroll
    for (int j = 0; j < 8; ++j) vv[j] = *(const float4*)(vp + nb + j * 4);
#pragma unroll
    for (int j = 0; j < 4; ++j) wvv[j] = *(const bf16x8*)(wvp + nb + j * 8);
    __syncthreads();
    gemm_small(sX, sW, acc, w, lrow, lkB);   // acc += P @ Wcat
    __syncthreads();
#pragma unroll
    for (int j = 0; j < 8; ++j) {
      bf16x4 h; h[0] = (bf16_t)vv[j].x; h[1] = (bf16_t)vv[j].y;
      h[2] = (bf16_t)vv[j].z; h[3] = (bf16_t)vv[j].w;
      int c = sseg * 32 + j * 4;
      *(bf16x4*)((char*)sX + (srow << 8) + ((c << 1) ^ ((srow & 7) << 4))) = h;
    }
#pragma unroll
    for (int j = 0; j < 4; ++j) {
      int c = sseg * 32 + j * 8;
      *(bf16x8*)((char*)sW + (srow << 8) + ((c << 1) ^ ((srow & 7) << 4))) = wvv[j];
    }
    // prefetch next-chunk P/Wcat (used after gemm2 + barrier)
    if (i < 15) {
      const int nb2 = (ncb + i + 1) * 128;
#pragma unroll
      for (int j = 0; j < 4; ++j) {
        hv[j] = *(const bf16x8*)(hbase + nb2 + j * 8);
        tv[j] = *(const bf16x8*)(tbase + nb2 + j * 8);
        wc[j] = *(const bf16x8*)(wcp + nb2 + j * 8);
      }
    }
    __syncthreads();
    gemm_small(sX, sW, acc, w, lrow, lkB);   // acc += Vis @ Wvcat
  }

  float* pa = pacc + ((size_t)blockIdx.y * 512 + blockIdx.x) * 64 * 64;
#pragma unroll
  for (int cf = 0; cf < 4; ++cf)
#pragma unroll
    for (int r = 0; r < 4; ++r) {
      int row = w * 16 + ((l >> 4) << 2) + r;
      pa[row * 64 + cf * 16 + lrow] = acc[cf][r];
    }
}

// ---------- k_fin: sum partials + bias + freq epilogue ----------
__global__ __launch_bounds__(256) void k_fin(const float* __restrict__ pacc,
                                             const float* __restrict__ bcv,
                                             const int* __restrict__ pair_pred,
                                             const float* __restrict__ freq,
                                             float* __restrict__ out) {
  int p = blockIdx.x * 256 + threadIdx.x;
  int g = p >> 6, row = p & 63;
  const float* a0 = pacc + ((size_t)g * 64 + row) * 64;
  const float* a1 = pacc + ((size_t)(512 + g) * 64 + row) * 64;
  const float* f = freq + ((size_t)pair_pred[p * 2] * 151 + pair_pred[p * 2 + 1]) * 51;
  float e1 = 0.f, e2 = 0.f, e3 = 0.f;
#pragma unroll
  for (int c = 0; c < 15; ++c) {
    float fb = f[GEO_c[c]]; e1 += expf(fb);
    out[(size_t)p * 15 + c] = a0[c] + a1[c] + bcv[c] + fb;
  }
#pragma unroll
  for (int c = 0; c < 11; ++c) {
    float fb = f[POS_c[c]]; e2 += expf(fb);
    out[491520 + (size_t)p * 11 + c] = a0[15 + c] + a1[15 + c] + bcv[15 + c] + fb;
  }
#pragma unroll
  for (int c = 0; c < 24; ++c) {
    float fb = f[SEM_c[c]]; e3 += expf(fb);
    out[851968 + (size_t)p * 24 + c] = a0[26 + c] + a1[26 + c] + bcv[26 + c] + fb;
  }
  out[1638400 + (size_t)p * 4 + 0] = a0[50] + a1[50] + bcv[50] + f[0];
  out[1638400 + (size_t)p * 4 + 1] = a0[51] + a1[51] + bcv[51] + logf(e1);
  out[1638400 + (size_t)p * 4 + 2] = a0[52] + a1[52] + bcv[52] + logf(e2);
  out[1638400 + (size_t)p * 4 + 3] = a0[53] + a1[53] + bcv[53] + logf(e3);
}

extern "C" void kernel_launch(void* const* d_in, const int* in_sizes, int n_in,
                              void* d_out, int out_size, void* d_ws, size_t ws_size,
                              hipStream_t stream) {
  const float* edge_ctx  = (const float*)d_in[0];
  const int*   pair_idx  = (const int*)d_in[1];
  const float* vis_rep   = (const float*)d_in[2];
  const int*   pair_pred = (const int*)d_in[3];
  const float* Wpe = (const float*)d_in[4];
  const float* bpe = (const float*)d_in[5];
  const float* Wpc = (const float*)d_in[6];
  const float* bpc = (const float*)d_in[7];
  const float* Wc1 = (const float*)d_in[8];  const float* bc1 = (const float*)d_in[9];
  const float* Wc2 = (const float*)d_in[10]; const float* bc2 = (const float*)d_in[11];
  const float* Wc3 = (const float*)d_in[12]; const float* bc3 = (const float*)d_in[13];
  const float* Wcs = (const float*)d_in[14]; const float* bcs = (const float*)d_in[15];
  const float* Wv1 = (const float*)d_in[16]; const float* bv1 = (const float*)d_in[17];
  const float* Wv2 = (const float*)d_in[18]; const float* bv2 = (const float*)d_in[19];
  const float* Wv3 = (const float*)d_in[20]; const float* bv3 = (const float*)d_in[21];
  const float* Wvs = (const float*)d_in[22]; const float* bvs = (const float*)d_in[23];
  const float* freq = (const float*)d_in[24];
  float* out = (float*)d_out;

  char* ws = (char*)d_ws;
  // layout (pacc aliases WpcT/W1T/W2T, which are dead before k_out2 runs):
  bf16_t* WpcT   = (bf16_t*)(ws + 0);           //  8388608
  bf16_t* W1T    = (bf16_t*)(ws + 8388608);     //  4194304
  bf16_t* W2T    = (bf16_t*)(ws + 12582912);    //  4194304
  float*  pacc   = (float*)(ws + 0);            // 16777216 (alias)
  bf16_t* ecb    = (bf16_t*)(ws + 16777216);    //  8388608
  bf16_t* WcatT  = (bf16_t*)(ws + 25165824);    //   524288
  bf16_t* WvcatT = (bf16_t*)(ws + 25690112);    //   524288
  float*  bcv    = (float*)(ws + 26214400);     //     4096 (pad)
  float*  b12    = (float*)(ws + 26218496);     //    32768
  bf16_t* HU     = (bf16_t*)(ws + 26251264);    // 67108864
  bf16_t* TU     = (bf16_t*)(ws + 93360128);    // 67108864  -> end 160468992

  k_transpose<<<dim3(64, 16), 256, 0, stream>>>(Wpc, WpcT, 1024, 4096);
  k_pack_cat<<<64, 256, 0, stream>>>(Wc1, Wc2, Wc3, Wcs, Wv1, Wv2, Wv3, Wvs,
                                     bc1, bc2, bc3, bcs, bv1, bv2, bv3, bvs,
                                     WcatT, WvcatT, bcv);
  k_ec<<<2048, 256, 0, stream>>>(edge_ctx, ecb);
  k_w12<<<dim3(4, 32, 2), 256, 0, stream>>>(WpcT, Wpe, W1T, W2T);
  k_bias<<<1024, 256, 0, stream>>>(WpcT, bpe, bpc, b12);
  k_ht2<<<dim3(32, 64, 2), 256, 0, stream>>>(ecb, W1T, W2T, b12, HU, TU);
  k_out2<<<dim3(512, 2), 256, 0, stream>>>(HU, TU, WcatT, WvcatT, pair_idx, vis_rep, pacc);
  k_fin<<<128, 256, 0, stream>>>(pacc, bcv, pair_pred, freq, out);
}